// Round 1
// baseline (550.938 us; speedup 1.0000x reference)
//
#include <hip/hip_runtime.h>

// LSTM: T=512, B=4096, I=10, H=20. Gate order i,f,g,o (PyTorch).
// Design: thread = (batch b, hidden j); owns all 4 gate rows for j.
//  - weights (4 rows x 30) live in VGPRs, loaded once (constant over t)
//  - wave = 20 j x 3 batch (60 active lanes): h exchange is intra-wave LDS,
//    NO __syncthreads anywhere -> no vmcnt(0) barrier drains
//  - x[t+1] prefetched into registers each step
//  - out writes: 60 consecutive dwords per block (coalesced)

#define T_STEPS 512
#define BATCH   4096
#define ISZ     10
#define HSZ     20
#define BPB     3    // batch per (one-wave) block: 20*3 = 60 active lanes

#if defined(__has_builtin)
#if __has_builtin(__builtin_amdgcn_exp2f)
#define FAST_EXP2(x) __builtin_amdgcn_exp2f(x)
#endif
#if __has_builtin(__builtin_amdgcn_rcpf)
#define FAST_RCP(x) __builtin_amdgcn_rcpf(x)
#endif
#endif
#ifndef FAST_EXP2
#define FAST_EXP2(x) exp2f(x)
#endif
#ifndef FAST_RCP
#define FAST_RCP(x) (1.0f/(x))
#endif

__device__ __forceinline__ float sigm_f(float x) {
    // 1/(1+e^-x) = 1/(1+2^(-x*log2e))
    return FAST_RCP(1.0f + FAST_EXP2(x * -1.4426950408889634f));
}
__device__ __forceinline__ float tanh_f(float x) {
    // tanh(x) = 2*sigmoid(2x)-1
    return 2.0f * FAST_RCP(1.0f + FAST_EXP2(x * -2.8853900817779268f)) - 1.0f;
}

__global__ __launch_bounds__(64, 2) void lstm_fused_kernel(
    const float* __restrict__ x,    // [T, B, I]
    const float* __restrict__ h0,   // [B, H]
    const float* __restrict__ c0,   // [B, H]
    const float* __restrict__ Wih,  // [4H, I]
    const float* __restrict__ Whh,  // [4H, H]
    const float* __restrict__ bih,  // [4H]
    const float* __restrict__ bhh,  // [4H]
    float* __restrict__ out)        // [T*B*H] ++ [B*H] ++ [B*H]
{
    // row pad 24 floats (96 B): rows start at banks 0/24/16 -> conflict-free,
    // and 96 % 16 == 0 so float4 reads stay aligned.
    __shared__ __align__(16) float hbuf[BPB][24];

    const int tid = threadIdx.x;
    const int b   = tid / HSZ;           // 0..3 (3 is idle)
    const int j   = tid % HSZ;           // 0..19
    const int gb  = blockIdx.x * BPB + b;
    if (tid >= BPB * HSZ || gb >= BATCH) return;

    // ---- hoist weights into VGPRs (constant over t) ----
    float w[4][ISZ + HSZ];
    float bias[4];
#pragma unroll
    for (int r = 0; r < 4; ++r) {
        const int row = r * HSZ + j;
#pragma unroll
        for (int k = 0; k < ISZ; ++k) w[r][k] = Wih[row * ISZ + k];
#pragma unroll
        for (int k = 0; k < HSZ; ++k) w[r][ISZ + k] = Whh[row * HSZ + k];
        bias[r] = bih[row] + bhh[row];
    }

    float c = c0[(size_t)gb * HSZ + j];
    hbuf[b][j] = h0[(size_t)gb * HSZ + j];   // wave-synchronous init

    const float* xbase = x + (size_t)gb * ISZ;   // step stride = BATCH*ISZ
    float* outp = out + (size_t)gb * HSZ + j;    // step stride = BATCH*HSZ

    // prefetch x[0] (float2: base is always 8B-aligned since 40*gb % 8 == 0)
    float2 nx[5];
    {
        const float2* xp = (const float2*)xbase;
#pragma unroll
        for (int q = 0; q < 5; ++q) nx[q] = xp[q];
    }

    float hn = hbuf[b][j];
    for (int t = 0; t < T_STEPS; ++t) {
        float cx[ISZ];
#pragma unroll
        for (int q = 0; q < 5; ++q) { cx[2*q] = nx[q].x; cx[2*q+1] = nx[q].y; }
        // issue next-step x loads early; consumed next iteration
        if (t + 1 < T_STEPS) {
            const float2* xp = (const float2*)(xbase + (size_t)(t + 1) * BATCH * ISZ);
#pragma unroll
            for (int q = 0; q < 5; ++q) nx[q] = xp[q];
        }

        // read h_t (written by this wave last iter; compiler orders via lgkmcnt)
        float hreg[HSZ];
        const float4* hrow = (const float4*)(&hbuf[b][0]);
#pragma unroll
        for (int q = 0; q < 5; ++q) {
            float4 v = hrow[q];
            hreg[4*q+0] = v.x; hreg[4*q+1] = v.y;
            hreg[4*q+2] = v.z; hreg[4*q+3] = v.w;
        }

        // gates: split accumulators to halve the FMA dependency chain
        float acc[4];
#pragma unroll
        for (int r = 0; r < 4; ++r) {
            float a0 = bias[r], a1 = 0.0f;
#pragma unroll
            for (int k = 0; k < ISZ; k += 2) {
                a0 += w[r][k]     * cx[k];
                a1 += w[r][k + 1] * cx[k + 1];
            }
#pragma unroll
            for (int k = 0; k < HSZ; k += 2) {
                a0 += w[r][ISZ + k]     * hreg[k];
                a1 += w[r][ISZ + k + 1] * hreg[k + 1];
            }
            acc[r] = a0 + a1;
        }

        const float ig = sigm_f(acc[0]);
        const float fg = sigm_f(acc[1]);
        const float gg = tanh_f(acc[2]);
        const float og = sigm_f(acc[3]);
        c  = fg * c + ig * gg;
        hn = og * tanh_f(c);

        hbuf[b][j] = hn;                          // publish h_{t+1} (intra-wave)
        outp[(size_t)t * (BATCH * HSZ)] = hn;     // coalesced: 60 consecutive dwords
    }

    // tail: final h then final c
    const size_t tail = (size_t)T_STEPS * BATCH * HSZ;
    out[tail + (size_t)gb * HSZ + j] = hn;
    out[tail + (size_t)BATCH * HSZ + (size_t)gb * HSZ + j] = c;
}

extern "C" void kernel_launch(void* const* d_in, const int* in_sizes, int n_in,
                              void* d_out, int out_size, void* d_ws, size_t ws_size,
                              hipStream_t stream) {
    const float* x   = (const float*)d_in[0];
    const float* h0  = (const float*)d_in[1];
    const float* c0  = (const float*)d_in[2];
    const float* Wih = (const float*)d_in[3];
    const float* Whh = (const float*)d_in[4];
    const float* bih = (const float*)d_in[5];
    const float* bhh = (const float*)d_in[6];
    float* out = (float*)d_out;

    const int nblk = (BATCH + BPB - 1) / BPB;   // 1366 one-wave blocks
    lstm_fused_kernel<<<nblk, 64, 0, stream>>>(x, h0, c0, Wih, Whh, bih, bhh, out);
}

// Round 2
// 476.714 us; speedup vs baseline: 1.1557x; 1.1557x over previous
//
#include <hip/hip_runtime.h>

// LSTM: T=512, B=4096, I=10, H=20. Gate order i,f,g,o (PyTorch).
// R2: deep x prefetch (PF=4), packed-f32 FMA (v_pk_fma_f32 via
// __builtin_elementwise_fma on float2), x-MACs scheduled to hide LDS h-read.
// Still: 1-wave blocks, no __syncthreads, weights in VGPRs.

#define T_STEPS 512
#define BATCH   4096
#define ISZ     10
#define HSZ     20
#define BPB     3    // batch per (one-wave) block: 20*3 = 60 active lanes
#define PF      4    // x prefetch depth (steps)
#define LDSPAD  22   // 22 words/row: max 2-way write conflict (free), 8B-aligned rows

typedef float v2f __attribute__((ext_vector_type(2)));

__device__ __forceinline__ v2f fma2(v2f a, v2f b, v2f c) {
    return __builtin_elementwise_fma(a, b, c);   // -> v_pk_fma_f32 on gfx950
}

#if defined(__has_builtin)
#if __has_builtin(__builtin_amdgcn_exp2f)
#define FAST_EXP2(x) __builtin_amdgcn_exp2f(x)
#endif
#if __has_builtin(__builtin_amdgcn_rcpf)
#define FAST_RCP(x) __builtin_amdgcn_rcpf(x)
#endif
#endif
#ifndef FAST_EXP2
#define FAST_EXP2(x) exp2f(x)
#endif
#ifndef FAST_RCP
#define FAST_RCP(x) (1.0f/(x))
#endif

__device__ __forceinline__ float sigm_f(float x) {
    return FAST_RCP(1.0f + FAST_EXP2(x * -1.4426950408889634f));
}
__device__ __forceinline__ float tanh_f(float x) {
    return 2.0f * FAST_RCP(1.0f + FAST_EXP2(x * -2.8853900817779268f)) - 1.0f;
}

__global__ __launch_bounds__(64, 1) void lstm_fused_kernel(
    const float* __restrict__ x,    // [T, B, I]
    const float* __restrict__ h0,   // [B, H]
    const float* __restrict__ c0,   // [B, H]
    const float* __restrict__ Wih,  // [4H, I]
    const float* __restrict__ Whh,  // [4H, H]
    const float* __restrict__ bih,  // [4H]
    const float* __restrict__ bhh,  // [4H]
    float* __restrict__ out)        // [T*B*H] ++ [B*H] ++ [B*H]
{
    __shared__ __align__(8) float hbuf[BPB][LDSPAD];

    const int tid = threadIdx.x;
    const int b   = tid / HSZ;           // 0..3 (3 is idle)
    const int j   = tid % HSZ;           // 0..19
    const int gb  = blockIdx.x * BPB + b;
    if (tid >= BPB * HSZ || gb >= BATCH) return;

    // ---- weights into VGPRs as packed pairs: wv[r][0..4]=Wih row, [5..14]=Whh row
    v2f wv[4][15];
    float bias[4];
#pragma unroll
    for (int r = 0; r < 4; ++r) {
        const int row = r * HSZ + j;
        const v2f* wi = (const v2f*)(Wih + row * ISZ);   // 40B*row -> 8B aligned
        const v2f* wh = (const v2f*)(Whh + row * HSZ);   // 80B*row -> 8B aligned
#pragma unroll
        for (int k = 0; k < 5; ++k)  wv[r][k] = wi[k];
#pragma unroll
        for (int k = 0; k < 10; ++k) wv[r][5 + k] = wh[k];
        bias[r] = bih[row] + bhh[row];
    }

    float c = c0[(size_t)gb * HSZ + j];
    hbuf[b][j] = h0[(size_t)gb * HSZ + j];   // wave-synchronous init

    const float* xbase = x + (size_t)gb * ISZ;   // step stride = BATCH*ISZ floats
    float* outp = out + (size_t)gb * HSZ + j;    // step stride = BATCH*HSZ floats

    // ---- prefetch x[0..PF-1] into circular register buffer
    v2f nx[PF][5];
#pragma unroll
    for (int p = 0; p < PF; ++p) {
        const v2f* xp = (const v2f*)(xbase + (size_t)p * BATCH * ISZ);
#pragma unroll
        for (int q = 0; q < 5; ++q) nx[p][q] = xp[q];
    }

    const v2f* hrow = (const v2f*)(&hbuf[b][0]);
    float hn = hbuf[b][j];

    for (int tb = 0; tb < T_STEPS; tb += PF) {
#pragma unroll
        for (int u = 0; u < PF; ++u) {
            const int t = tb + u;

            // 1) issue h reads early (critical path)
            v2f hv[10];
#pragma unroll
            for (int q = 0; q < 10; ++q) hv[q] = hrow[q];

            // 2) x-part MACs (no h dependency -> fills LDS read latency)
            v2f a[4];
#pragma unroll
            for (int r = 0; r < 4; ++r) {
                a[r] = (v2f){bias[r], 0.0f};
#pragma unroll
                for (int k = 0; k < 5; ++k) a[r] = fma2(wv[r][k], nx[u][k], a[r]);
            }

            // 3) refill slot u with x[t+PF] (clamped; redundant loads at tail)
            {
                int tp = t + PF; if (tp > T_STEPS - 1) tp = T_STEPS - 1;
                const v2f* xp = (const v2f*)(xbase + (size_t)tp * BATCH * ISZ);
#pragma unroll
                for (int q = 0; q < 5; ++q) nx[u][q] = xp[q];
            }

            // 4) h-part MACs
#pragma unroll
            for (int r = 0; r < 4; ++r) {
#pragma unroll
                for (int k = 0; k < 10; ++k) a[r] = fma2(wv[r][5 + k], hv[k], a[r]);
            }

            const float ig = sigm_f(a[0].x + a[0].y);
            const float fg = sigm_f(a[1].x + a[1].y);
            const float gg = tanh_f(a[2].x + a[2].y);
            const float og = sigm_f(a[3].x + a[3].y);
            c  = fg * c + ig * gg;
            hn = og * tanh_f(c);

            hbuf[b][j] = hn;                          // publish h_{t+1} (intra-wave)
            outp[(size_t)t * (BATCH * HSZ)] = hn;     // coalesced 60-dword burst
        }
    }

    // tail: final h then final c
    const size_t tail = (size_t)T_STEPS * BATCH * HSZ;
    out[tail + (size_t)gb * HSZ + j] = hn;
    out[tail + (size_t)BATCH * HSZ + (size_t)gb * HSZ + j] = c;
}

extern "C" void kernel_launch(void* const* d_in, const int* in_sizes, int n_in,
                              void* d_out, int out_size, void* d_ws, size_t ws_size,
                              hipStream_t stream) {
    const float* x   = (const float*)d_in[0];
    const float* h0  = (const float*)d_in[1];
    const float* c0  = (const float*)d_in[2];
    const float* Wih = (const float*)d_in[3];
    const float* Whh = (const float*)d_in[4];
    const float* bih = (const float*)d_in[5];
    const float* bhh = (const float*)d_in[6];
    float* out = (float*)d_out;

    const int nblk = (BATCH + BPB - 1) / BPB;   // 1366 one-wave blocks
    lstm_fused_kernel<<<nblk, 64, 0, stream>>>(x, h0, c0, Wih, Whh, bih, bhh, out);
}